// Round 2
// baseline (420.091 us; speedup 1.0000x reference)
//
#include <hip/hip_runtime.h>
#include <hip/hip_bf16.h>

// Problem constants (B,T,E,H) = (4, 2048, 1024, 64); scale = E^-0.5 = 1/32.
constexpr int Bc = 4;
constexpr int Tc = 2048;
constexpr int Ec = 1024;
constexpr int Hc = 64;
constexpr float MASKV = -30000.0f;   // exp-safe stand-in for -inf

__device__ __forceinline__ float bf2f(unsigned int u16) {  // low 16 bits = bf16
    union { unsigned int i; float f; } x;
    x.i = (u16 & 0xffffu) << 16;
    return x.f;
}
__device__ __forceinline__ unsigned short f2bf(float f) {  // round-to-nearest-even
    union { float f; unsigned int i; } x;
    x.f = f;
    unsigned int r = x.i + 0x7fffu + ((x.i >> 16) & 1u);
    return (unsigned short)(r >> 16);
}
__device__ __forceinline__ void dec8(uint4 u, float* d) {  // 8 packed bf16 -> fp32
    d[0] = bf2f(u.x); d[1] = bf2f(u.x >> 16);
    d[2] = bf2f(u.y); d[3] = bf2f(u.y >> 16);
    d[4] = bf2f(u.z); d[5] = bf2f(u.z >> 16);
    d[6] = bf2f(u.w); d[7] = bf2f(u.w >> 16);
}

// ---------------------------------------------------------------------------
// Dtype probe: packed-bf16 pairs have a plausible bf16 exponent (~127) in the
// LOWER 16 bits of ~every word; fp32 words have random low-mantissa bits there
// (~16% plausible). flag=1 -> bf16, flag=0 -> fp32. 1 wave, 1024 words of X.
// ---------------------------------------------------------------------------
__global__ void detect_dtype(const unsigned int* __restrict__ Xw, int* __restrict__ flag)
{
    const int lane = threadIdx.x;  // 64 threads
    int cnt = 0;
    #pragma unroll
    for (int i = 0; i < 16; ++i) {
        unsigned int w = Xw[lane * 16 + i];
        unsigned int elo = (w >> 7) & 0xffu;      // lower half as bf16: exponent
        cnt += (elo >= 100u && elo <= 150u) ? 1 : 0;
    }
    cnt += __shfl_xor(cnt, 1);
    cnt += __shfl_xor(cnt, 2);
    cnt += __shfl_xor(cnt, 4);
    cnt += __shfl_xor(cnt, 8);
    cnt += __shfl_xor(cnt, 16);
    cnt += __shfl_xor(cnt, 32);
    if (lane == 0) flag[0] = (cnt >= 600) ? 1 : 0;
}

// ---------------------------------------------------------------------------
// Kernel 1: fused QKV projection. Q/K/V = X @ Wq/Wk/Wv, bf16 out to ws.
// Block: 256 threads = 4 waves; wave w computes 4 rows x 64 cols (h=lane).
// Grid: B*T/16 = 512 blocks. Dtype chosen by device flag (uniform branch).
// ---------------------------------------------------------------------------
template <bool BF16>
__device__ __forceinline__ void qkv_body(
    const void* __restrict__ Xv, const void* __restrict__ Wqv,
    const void* __restrict__ Wkv, const void* __restrict__ Wvv,
    unsigned short* __restrict__ Qo, unsigned short* __restrict__ Ko,
    unsigned short* __restrict__ Vo, float (*Xs)[Ec])
{
    const int tid  = threadIdx.x;
    const int w    = tid >> 6;
    const int lane = tid & 63;
    const long row0 = (long)blockIdx.x * 16;

    if (BF16) {
        const unsigned short* X = (const unsigned short*)Xv;
        for (int r = 0; r < 4; ++r) {
            const uint4* s4 = reinterpret_cast<const uint4*>(X + (row0 + w * 4 + r) * Ec);
            #pragma unroll
            for (int i = 0; i < 2; ++i) {
                uint4 u = s4[lane + 64 * i];
                dec8(u, &Xs[w * 4 + r][(lane + 64 * i) * 8]);
            }
        }
    } else {
        const float* X = (const float*)Xv;
        for (int r = 0; r < 4; ++r) {
            const float4* s4 = reinterpret_cast<const float4*>(X + (row0 + w * 4 + r) * Ec);
            #pragma unroll
            for (int i = 0; i < 4; ++i) {
                float4 f = s4[lane + 64 * i];
                float* d = &Xs[w * 4 + r][(lane + 64 * i) * 4];
                d[0] = f.x; d[1] = f.y; d[2] = f.z; d[3] = f.w;
            }
        }
    }
    __syncthreads();

    float qa[4] = {0.f, 0.f, 0.f, 0.f};
    float ka[4] = {0.f, 0.f, 0.f, 0.f};
    float va[4] = {0.f, 0.f, 0.f, 0.f};

    #pragma unroll 4
    for (int e = 0; e < Ec; ++e) {
        float wq, wk, wv;
        if (BF16) {
            wq = bf2f(((const unsigned short*)Wqv)[e * Hc + lane]);
            wk = bf2f(((const unsigned short*)Wkv)[e * Hc + lane]);
            wv = bf2f(((const unsigned short*)Wvv)[e * Hc + lane]);
        } else {
            wq = ((const float*)Wqv)[e * Hc + lane];
            wk = ((const float*)Wkv)[e * Hc + lane];
            wv = ((const float*)Wvv)[e * Hc + lane];
        }
        #pragma unroll
        for (int r = 0; r < 4; ++r) {
            const float x = Xs[w * 4 + r][e];   // all-lane broadcast
            qa[r] += x * wq;
            ka[r] += x * wk;
            va[r] += x * wv;
        }
    }

    #pragma unroll
    for (int r = 0; r < 4; ++r) {
        const long row = row0 + w * 4 + r;
        Qo[row * Hc + lane] = f2bf(qa[r]);
        Ko[row * Hc + lane] = f2bf(ka[r]);
        Vo[row * Hc + lane] = f2bf(va[r]);
    }
}

__global__ __launch_bounds__(256) void qkv_kernel(
    const void* Xv, const void* Wqv, const void* Wkv, const void* Wvv,
    unsigned short* Qo, unsigned short* Ko, unsigned short* Vo,
    const int* __restrict__ flag)
{
    __shared__ float Xs[16][Ec];   // 64 KB
    if (flag[0]) qkv_body<true>(Xv, Wqv, Wkv, Wvv, Qo, Ko, Vo, Xs);
    else         qkv_body<false>(Xv, Wqv, Wkv, Wvv, Qo, Ko, Vo, Xs);
}

// ---------------------------------------------------------------------------
// Kernel 2: causal flash attention (online softmax). bf16 Q/K/V from ws.
// Block: 128 threads; Q-tile 32, K-tile 64; thread (qg,kg) owns 4x4 of S / O.
// Row stats reduced over the 16 kg lanes via __shfl_xor. Grid: B*T/32 = 256.
// ---------------------------------------------------------------------------
__global__ __launch_bounds__(128) void attn_kernel(
    const unsigned short* __restrict__ Q, const unsigned short* __restrict__ K,
    const unsigned short* __restrict__ V, void* __restrict__ OutV,
    const int* __restrict__ flag)
{
    __shared__ float Qs[32][65];
    __shared__ float Ks[64][65];
    __shared__ float Vs[64][65];
    __shared__ float Ps[32][68];

    const int tid = threadIdx.x;
    const int qg  = tid >> 4;       // 0..7
    const int kg  = tid & 15;       // 0..15
    const int q0  = qg * 4;
    const int c0  = kg * 4;
    const int b   = blockIdx.x >> 6;
    const int qt  = blockIdx.x & 63;
    const float scale = 0.03125f;   // 1/sqrt(1024)
    const bool obf16 = (flag[0] != 0);

    // Stage Q tile (32x64 bf16 -> fp32): 256 uint4s.
    const uint4* Qg = reinterpret_cast<const uint4*>(Q + ((size_t)b * Tc + qt * 32) * Hc);
    for (int i = tid; i < 32 * 8; i += 128) {
        dec8(Qg[i], &Qs[i >> 3][(i & 7) * 8]);
    }

    float m[4], l[4], acc[4][4];
    #pragma unroll
    for (int i = 0; i < 4; ++i) {
        m[i] = MASKV; l[i] = 0.f;
        #pragma unroll
        for (int j = 0; j < 4; ++j) acc[i][j] = 0.f;
    }

    const int ktiles = qt / 2 + 1;

    for (int kt = 0; kt < ktiles; ++kt) {
        __syncthreads();   // protect K/V/P LDS from previous iteration's readers
        const uint4* Kg = reinterpret_cast<const uint4*>(K + ((size_t)b * Tc + kt * 64) * Hc);
        const uint4* Vg = reinterpret_cast<const uint4*>(V + ((size_t)b * Tc + kt * 64) * Hc);
        for (int i = tid; i < 64 * 8; i += 128) {
            dec8(Kg[i], &Ks[i >> 3][(i & 7) * 8]);
            dec8(Vg[i], &Vs[i >> 3][(i & 7) * 8]);
        }
        __syncthreads();

        // S = Q K^T (32x64 tile), 4x4 per thread.
        float s[4][4];
        #pragma unroll
        for (int i = 0; i < 4; ++i)
            #pragma unroll
            for (int j = 0; j < 4; ++j) s[i][j] = 0.f;

        for (int e = 0; e < Hc; ++e) {
            const float x0 = Qs[q0 + 0][e], x1 = Qs[q0 + 1][e];
            const float x2 = Qs[q0 + 2][e], x3 = Qs[q0 + 3][e];
            const float y0 = Ks[c0 + 0][e], y1 = Ks[c0 + 1][e];
            const float y2 = Ks[c0 + 2][e], y3 = Ks[c0 + 3][e];
            s[0][0] += x0 * y0; s[0][1] += x0 * y1; s[0][2] += x0 * y2; s[0][3] += x0 * y3;
            s[1][0] += x1 * y0; s[1][1] += x1 * y1; s[1][2] += x1 * y2; s[1][3] += x1 * y3;
            s[2][0] += x2 * y0; s[2][1] += x2 * y1; s[2][2] += x2 * y2; s[2][3] += x2 * y3;
            s[3][0] += x3 * y0; s[3][1] += x3 * y1; s[3][2] += x3 * y2; s[3][3] += x3 * y3;
        }

        // Scale, causal mask, online softmax update.
        const int kbase = kt * 64 + c0;
        #pragma unroll
        for (int i = 0; i < 4; ++i) {
            const int qi = qt * 32 + q0 + i;
            float mx = MASKV;
            #pragma unroll
            for (int j = 0; j < 4; ++j) {
                float v = s[i][j] * scale;
                if (kbase + j > qi) v = MASKV;
                s[i][j] = v;
                mx = fmaxf(mx, v);
            }
            mx = fmaxf(mx, __shfl_xor(mx, 1));
            mx = fmaxf(mx, __shfl_xor(mx, 2));
            mx = fmaxf(mx, __shfl_xor(mx, 4));
            mx = fmaxf(mx, __shfl_xor(mx, 8));
            const float mnew  = fmaxf(m[i], mx);
            const float alpha = __expf(m[i] - mnew);   // args in [-60000, 0]
            m[i] = mnew;
            float sum = 0.f;
            #pragma unroll
            for (int j = 0; j < 4; ++j) {
                const float p = __expf(s[i][j] - mnew);
                s[i][j] = p;
                sum += p;
            }
            sum += __shfl_xor(sum, 1);
            sum += __shfl_xor(sum, 2);
            sum += __shfl_xor(sum, 4);
            sum += __shfl_xor(sum, 8);
            l[i] = l[i] * alpha + sum;
            #pragma unroll
            for (int j = 0; j < 4; ++j) acc[i][j] *= alpha;
            *reinterpret_cast<float4*>(&Ps[q0 + i][c0]) =
                make_float4(s[i][0], s[i][1], s[i][2], s[i][3]);
        }
        __syncthreads();   // P visible before PV

        // O += P V; thread owns O[q0..q0+3][c0..c0+3].
        for (int k = 0; k < 64; ++k) {
            const float p0 = Ps[q0 + 0][k], p1 = Ps[q0 + 1][k];
            const float p2 = Ps[q0 + 2][k], p3 = Ps[q0 + 3][k];
            const float v0 = Vs[k][c0 + 0], v1 = Vs[k][c0 + 1];
            const float v2 = Vs[k][c0 + 2], v3 = Vs[k][c0 + 3];
            acc[0][0] += p0 * v0; acc[0][1] += p0 * v1; acc[0][2] += p0 * v2; acc[0][3] += p0 * v3;
            acc[1][0] += p1 * v0; acc[1][1] += p1 * v1; acc[1][2] += p1 * v2; acc[1][3] += p1 * v3;
            acc[2][0] += p2 * v0; acc[2][1] += p2 * v1; acc[2][2] += p2 * v2; acc[2][3] += p2 * v3;
            acc[3][0] += p3 * v0; acc[3][1] += p3 * v1; acc[3][2] += p3 * v2; acc[3][3] += p3 * v3;
        }
    }

    // Epilogue: O / l; store in the detected output dtype.
    const size_t obase = ((size_t)b * Tc + qt * 32) * Hc;
    if (obf16) {
        unsigned short* O = (unsigned short*)OutV;
        #pragma unroll
        for (int i = 0; i < 4; ++i) {
            const float inv = 1.f / l[i];
            #pragma unroll
            for (int j = 0; j < 4; ++j)
                O[obase + (q0 + i) * Hc + c0 + j] = f2bf(acc[i][j] * inv);
        }
    } else {
        float* O = (float*)OutV;
        #pragma unroll
        for (int i = 0; i < 4; ++i) {
            const float inv = 1.f / l[i];
            #pragma unroll
            for (int j = 0; j < 4; ++j)
                O[obase + (q0 + i) * Hc + c0 + j] = acc[i][j] * inv;
        }
    }
}

extern "C" void kernel_launch(void* const* d_in, const int* in_sizes, int n_in,
                              void* d_out, int out_size, void* d_ws, size_t ws_size,
                              hipStream_t stream)
{
    const size_t N = (size_t)Bc * Tc * Hc;   // 524288 elems per Q/K/V

    unsigned short* Qws = (unsigned short*)d_ws;            // 1 MB
    unsigned short* Kws = Qws + N;                          // 1 MB
    unsigned short* Vws = Kws + N;                          // 1 MB
    int* flag = (int*)((char*)d_ws + 3 * N * sizeof(unsigned short));

    detect_dtype<<<dim3(1), dim3(64), 0, stream>>>(
        (const unsigned int*)d_in[0], flag);
    qkv_kernel<<<dim3((Bc * Tc) / 16), dim3(256), 0, stream>>>(
        d_in[0], d_in[1], d_in[2], d_in[3], Qws, Kws, Vws, flag);
    attn_kernel<<<dim3(Bc * (Tc / 32)), dim3(128), 0, stream>>>(
        Qws, Kws, Vws, d_out, flag);
}

// Round 7
// 137.591 us; speedup vs baseline: 3.0532x; 3.0532x over previous
//
#include <hip/hip_runtime.h>
#include <hip/hip_bf16.h>

// (B,T,E,H) = (4, 2048, 1024, 64); scale = E^-0.5 = 1/32.
// Ground truth established r2+r6: inputs fp32, OUTPUT fp32 (r2 passed via its
// fp32 branch: detect_dtype cnt~204<600 on fp32 data -> flag=0 path).
constexpr int Bc = 4;
constexpr int Tc = 2048;
constexpr int Ec = 1024;
constexpr int Hc = 64;
constexpr float SCALE  = 0.03125f;    // 1/sqrt(1024)
constexpr float M_INIT = -30000.0f;
constexpr float MASK_S = -1.0e8f;     // exp(MASK_S - m) == 0 for m >= M_INIT

typedef short  short8  __attribute__((ext_vector_type(8)));
typedef float  floatx4 __attribute__((ext_vector_type(4)));

__device__ __forceinline__ unsigned short f2bf(float f) {  // RNE
    union { float f; unsigned int i; } x;
    x.f = f;
    unsigned int r = x.i + 0x7fffu + ((x.i >> 16) & 1u);
    return (unsigned short)(r >> 16);
}
__device__ __forceinline__ short8 pack8(float4 f0, float4 f1) {
    short8 v;
    v[0] = (short)f2bf(f0.x); v[1] = (short)f2bf(f0.y);
    v[2] = (short)f2bf(f0.z); v[3] = (short)f2bf(f0.w);
    v[4] = (short)f2bf(f1.x); v[5] = (short)f2bf(f1.y);
    v[6] = (short)f2bf(f1.z); v[7] = (short)f2bf(f1.w);
    return v;
}

// ---------------------------------------------------------------------------
// Kernel 0: convert+transpose weights. W fp32 [E][H] -> Wt bf16 [H][E], x3.
// Wt lives in d_out scratch (384 KB of the 2 MB fp32 out buffer; attn fully
// overwrites d_out afterwards). Grid (64,3) x 256 thr.
// ---------------------------------------------------------------------------
__global__ __launch_bounds__(256) void prep_w(
    const float* __restrict__ Wq, const float* __restrict__ Wk,
    const float* __restrict__ Wv, unsigned short* __restrict__ Wt)
{
    const float* W = blockIdx.y == 0 ? Wq : (blockIdx.y == 1 ? Wk : Wv);
    unsigned short* D = Wt + (size_t)blockIdx.y * (Ec * Hc);
    const int i0 = blockIdx.x * 1024 + threadIdx.x * 4;
    const float4 f = *(const float4*)(W + i0);
    const float v[4] = {f.x, f.y, f.z, f.w};
    #pragma unroll
    for (int j = 0; j < 4; ++j) {
        const int i = i0 + j;           // i = e*64 + h
        const int e = i >> 6, h = i & 63;
        D[h * Ec + e] = f2bf(v[j]);
    }
}

// ---------------------------------------------------------------------------
// Kernel 1: QKV projection, MFMA 16x16x32 bf16 — no LDS, no barriers.
// A-frags: X fp32 rows, 2 x float4 per lane -> f2bf -> short8.
// B-frags: Wt bf16 rows (W columns), contiguous 16 B/lane (m97 B^T pattern).
// Grid (64,3): x = 128-row tile, y = which matrix. Wave w owns 32 rows.
// Sanitizer: |acc|>=1e4 or non-finite -> 11111 (decode: "qkv MFMA garbage").
// ---------------------------------------------------------------------------
__global__ __launch_bounds__(256) void qkv_mfma3(
    const float* __restrict__ X, const unsigned short* __restrict__ Wt,
    unsigned short* __restrict__ Qo, unsigned short* __restrict__ Ko,
    unsigned short* __restrict__ Vo)
{
    const int tid  = threadIdx.x;
    const int wv   = tid >> 6;
    const int lane = tid & 63;
    const int quad = lane >> 4;
    const int l16  = lane & 15;
    const int which = blockIdx.y;
    const unsigned short* Wm = Wt + (size_t)which * (Ec * Hc);  // bf16 [64][1024]
    unsigned short* O = which == 0 ? Qo : (which == 1 ? Ko : Vo);
    const size_t rowbase = (size_t)blockIdx.x * 128 + wv * 32;

    floatx4 acc[2][4];
    #pragma unroll
    for (int mi = 0; mi < 2; ++mi)
        #pragma unroll
        for (int ni = 0; ni < 4; ++ni)
            #pragma unroll
            for (int r = 0; r < 4; ++r) acc[mi][ni][r] = 0.f;

    const float* xr0 = X + (rowbase + 0  + l16) * Ec + quad * 8;
    const float* xr1 = X + (rowbase + 16 + l16) * Ec + quad * 8;
    const unsigned short* wb0 = Wm + (0  + l16) * Ec + quad * 8;
    const unsigned short* wb1 = Wm + (16 + l16) * Ec + quad * 8;
    const unsigned short* wb2 = Wm + (32 + l16) * Ec + quad * 8;
    const unsigned short* wb3 = Wm + (48 + l16) * Ec + quad * 8;

    for (int k0 = 0; k0 < Ec; k0 += 32) {
        const short8 a0 = pack8(*(const float4*)(xr0 + k0),
                                *(const float4*)(xr0 + k0 + 4));
        const short8 a1 = pack8(*(const float4*)(xr1 + k0),
                                *(const float4*)(xr1 + k0 + 4));
        const short8 b0 = *(const short8*)(wb0 + k0);
        const short8 b1 = *(const short8*)(wb1 + k0);
        const short8 b2 = *(const short8*)(wb2 + k0);
        const short8 b3 = *(const short8*)(wb3 + k0);
        acc[0][0] = __builtin_amdgcn_mfma_f32_16x16x32_bf16(a0, b0, acc[0][0], 0, 0, 0);
        acc[0][1] = __builtin_amdgcn_mfma_f32_16x16x32_bf16(a0, b1, acc[0][1], 0, 0, 0);
        acc[0][2] = __builtin_amdgcn_mfma_f32_16x16x32_bf16(a0, b2, acc[0][2], 0, 0, 0);
        acc[0][3] = __builtin_amdgcn_mfma_f32_16x16x32_bf16(a0, b3, acc[0][3], 0, 0, 0);
        acc[1][0] = __builtin_amdgcn_mfma_f32_16x16x32_bf16(a1, b0, acc[1][0], 0, 0, 0);
        acc[1][1] = __builtin_amdgcn_mfma_f32_16x16x32_bf16(a1, b1, acc[1][1], 0, 0, 0);
        acc[1][2] = __builtin_amdgcn_mfma_f32_16x16x32_bf16(a1, b2, acc[1][2], 0, 0, 0);
        acc[1][3] = __builtin_amdgcn_mfma_f32_16x16x32_bf16(a1, b3, acc[1][3], 0, 0, 0);
    }

    // C/D layout: col = lane&15, row = quad*4 + reg (guide m89/m91).
    #pragma unroll
    for (int mi = 0; mi < 2; ++mi)
        #pragma unroll
        for (int ni = 0; ni < 4; ++ni)
            #pragma unroll
            for (int r = 0; r < 4; ++r) {
                float x = acc[mi][ni][r];
                if (!(x > -1.0e4f && x < 1.0e4f)) x = 11111.0f;  // diagnostic
                const size_t row = rowbase + mi * 16 + quad * 4 + r;
                O[row * Hc + 16 * ni + l16] = f2bf(x);
            }
}

// ---------------------------------------------------------------------------
// Kernel 2: causal flash attention, MFMA 16x16x32 bf16 (r3 structure,
// re-audited; bf16 Q/K/V from ws, fp32 output).
// Grid (128,4): (16-row q-tile, batch). 4 waves; wave w owns k-subtile
// [kb0+64w, +64) with private online-softmax state; no mid-round barriers.
// V staged transposed in LDS with XOR-8 bank swizzle. P: C-layout -> wave-
// private LDS -> A-layout. 4-way merge at end. Sanitizer sentinel 555.
// ---------------------------------------------------------------------------
__global__ __launch_bounds__(256) void attn_mfma2(
    const unsigned short* __restrict__ Q, const unsigned short* __restrict__ K,
    const unsigned short* __restrict__ V, float* __restrict__ Out)
{
    __shared__ __align__(16) unsigned short Vt[64][256];   // 32 KB [h][k^swz]
    __shared__ __align__(16) unsigned short Pb[4][16][72]; // 9.2 KB per-wave P

    const int tid  = threadIdx.x;
    const int wv   = tid >> 6;
    const int lane = tid & 63;
    const int quad = lane >> 4;
    const int l16  = lane & 15;
    const int qt   = blockIdx.x;          // 0..127
    const int b    = blockIdx.y;
    const int qend = qt * 16 + 16;
    const int rounds = (qend + 255) >> 8;
    const size_t base = (size_t)b * Tc * Hc;

    short8 aQ[2];
    #pragma unroll
    for (int ks = 0; ks < 2; ++ks)
        aQ[ks] = *(const short8*)(Q + base + (size_t)(qt * 16 + l16) * Hc + ks * 32 + quad * 8);

    floatx4 acc[4];
    float m_st[4], l_st[4];
    #pragma unroll
    for (int nh = 0; nh < 4; ++nh)
        #pragma unroll
        for (int r = 0; r < 4; ++r) acc[nh][r] = 0.f;
    #pragma unroll
    for (int r = 0; r < 4; ++r) { m_st[r] = M_INIT; l_st[r] = 0.f; }

    for (int rd = 0; rd < rounds; ++rd) {
        const int kb0 = rd * 256;
        __syncthreads();   // protect Vt from previous round's readers
        {   // stage V[kb0..kb0+256) transposed: Vt[h][k ^ 8*(h>>3)]
            const int hg  = tid & 7;
            const int kr0 = (tid >> 3) * 8;
            uint4 u[8];
            #pragma unroll
            for (int r = 0; r < 8; ++r)
                u[r] = *(const uint4*)(V + base + (size_t)(kb0 + kr0 + r) * Hc + hg * 8);
            #pragma unroll
            for (int j = 0; j < 8; ++j) {
                unsigned int e[8];
                #pragma unroll
                for (int r = 0; r < 8; ++r) {
                    const unsigned int* pw = (const unsigned int*)&u[r];
                    e[r] = (pw[j >> 1] >> (16 * (j & 1))) & 0xffffu;
                }
                uint4 w;
                w.x = e[0] | (e[1] << 16); w.y = e[2] | (e[3] << 16);
                w.z = e[4] | (e[5] << 16); w.w = e[6] | (e[7] << 16);
                *(uint4*)&Vt[hg * 8 + j][kr0 ^ (8 * hg)] = w;
            }
        }
        __syncthreads();

        const int kbase = kb0 + wv * 64;
        if (kbase < qend) {
            floatx4 s[4];
            #pragma unroll
            for (int ni = 0; ni < 4; ++ni)
                #pragma unroll
                for (int r = 0; r < 4; ++r) s[ni][r] = 0.f;
            #pragma unroll
            for (int ks = 0; ks < 2; ++ks) {
                short8 bk[4];
                #pragma unroll
                for (int ni = 0; ni < 4; ++ni)
                    bk[ni] = *(const short8*)(K + base +
                        (size_t)(kbase + 16 * ni + l16) * Hc + ks * 32 + quad * 8);
                #pragma unroll
                for (int ni = 0; ni < 4; ++ni)
                    s[ni] = __builtin_amdgcn_mfma_f32_16x16x32_bf16(aQ[ks], bk[ni], s[ni], 0, 0, 0);
            }

            float alpha[4];
            #pragma unroll
            for (int r = 0; r < 4; ++r) {
                const int qrow = qt * 16 + quad * 4 + r;
                float mr = MASK_S;
                #pragma unroll
                for (int ni = 0; ni < 4; ++ni) {
                    const int kcol = kbase + 16 * ni + l16;
                    float v = s[ni][r] * SCALE;
                    if (kcol > qrow) v = MASK_S;
                    s[ni][r] = v;
                    mr = fmaxf(mr, v);
                }
                mr = fmaxf(mr, __shfl_xor(mr, 1));
                mr = fmaxf(mr, __shfl_xor(mr, 2));
                mr = fmaxf(mr, __shfl_xor(mr, 4));
                mr = fmaxf(mr, __shfl_xor(mr, 8));
                const float mnew = fmaxf(m_st[r], mr);
                alpha[r] = __expf(m_st[r] - mnew);
                m_st[r] = mnew;
                float sum = 0.f;
                #pragma unroll
                for (int ni = 0; ni < 4; ++ni) {
                    const float p = __expf(s[ni][r] - mnew);
                    s[ni][r] = p;
                    sum += p;
                }
                sum += __shfl_xor(sum, 1);
                sum += __shfl_xor(sum, 2);
                sum += __shfl_xor(sum, 4);
                sum += __shfl_xor(sum, 8);
                l_st[r] = l_st[r] * alpha[r] + sum;
            }
            #pragma unroll
            for (int ni = 0; ni < 4; ++ni)
                #pragma unroll
                for (int r = 0; r < 4; ++r) {
                    acc[ni][r] *= alpha[r];
                    Pb[wv][quad * 4 + r][16 * ni + l16] = f2bf(s[ni][r]);
                }

            #pragma unroll
            for (int ks = 0; ks < 2; ++ks) {
                const short8 aP = *(const short8*)&Pb[wv][l16][ks * 32 + quad * 8];
                short8 bvv[4];
                #pragma unroll
                for (int nh = 0; nh < 4; ++nh) {
                    const int hh = 16 * nh + l16;
                    const int kc = (wv * 64 + ks * 32 + quad * 8) ^ (8 * (hh >> 3));
                    bvv[nh] = *(const short8*)&Vt[hh][kc];
                }
                #pragma unroll
                for (int nh = 0; nh < 4; ++nh)
                    acc[nh] = __builtin_amdgcn_mfma_f32_16x16x32_bf16(aP, bvv[nh], acc[nh], 0, 0, 0);
            }
        }
    }

    // ---- merge 4 per-wave states; fp32 output ----
    __syncthreads();
    float* accS = (float*)&Vt[0][0];          // 4 x 16 x 64 fp32 = 16 KB
    float* mlS  = (float*)&Pb[0][0][0];       // 4 x 16 x {m,l}
    #pragma unroll
    for (int nh = 0; nh < 4; ++nh)
        #pragma unroll
        for (int r = 0; r < 4; ++r)
            accS[wv * 1024 + (quad * 4 + r) * 64 + 16 * nh + l16] = acc[nh][r];
    if (l16 == 0) {
        #pragma unroll
        for (int r = 0; r < 4; ++r) {
            const int row = quad * 4 + r;
            mlS[(wv * 16 + row) * 2 + 0] = m_st[r];
            mlS[(wv * 16 + row) * 2 + 1] = l_st[r];
        }
    }
    __syncthreads();
    {
        const int q  = tid >> 4;              // 0..15
        const int h0 = (tid & 15) * 4;        // 0..60
        float mw[4], lw[4], M = -3.4e38f;
        #pragma unroll
        for (int w = 0; w < 4; ++w) {
            mw[w] = mlS[(w * 16 + q) * 2 + 0];
            lw[w] = mlS[(w * 16 + q) * 2 + 1];
            M = fmaxf(M, mw[w]);
        }
        float coef[4], denom = 0.f;
        #pragma unroll
        for (int w = 0; w < 4; ++w) {
            coef[w] = __expf(mw[w] - M);
            denom += coef[w] * lw[w];
        }
        const float inv = 1.f / denom;
        float4 st;
        float* sp = &st.x;
        #pragma unroll
        for (int j = 0; j < 4; ++j) {
            float o = 0.f;
            #pragma unroll
            for (int w = 0; w < 4; ++w)
                o += coef[w] * accS[w * 1024 + q * 64 + h0 + j];
            o *= inv;
            if (!(o > -1.0e5f && o < 1.0e5f)) o = 555.0f;   // diagnostic
            sp[j] = o;
        }
        *(float4*)(Out + base + (size_t)(qt * 16 + q) * Hc + h0) = st;
    }
}

extern "C" void kernel_launch(void* const* d_in, const int* in_sizes, int n_in,
                              void* d_out, int out_size, void* d_ws, size_t ws_size,
                              hipStream_t stream)
{
    const float* X  = (const float*)d_in[0];
    const float* Wq = (const float*)d_in[1];
    const float* Wk = (const float*)d_in[2];
    const float* Wv = (const float*)d_in[3];

    const size_t N = (size_t)Bc * Tc * Hc;                  // 524,288
    unsigned short* Qws = (unsigned short*)d_ws;            // 1 MB
    unsigned short* Kws = Qws + N;                          // 1 MB
    unsigned short* Vws = Kws + N;                          // 1 MB (3 MB, proven)

    // d_out = 2 MB fp32 (r2-proven). First 384 KB used as Wt scratch; the
    // attention kernel fully overwrites d_out afterwards.
    unsigned short* Wt = (unsigned short*)d_out;

    prep_w<<<dim3(64, 3), dim3(256), 0, stream>>>(Wq, Wk, Wv, Wt);
    qkv_mfma3<<<dim3(64, 3), dim3(256), 0, stream>>>(X, Wt, Qws, Kws, Vws);
    attn_mfma2<<<dim3(128, 4), dim3(256), 0, stream>>>(
        Qws, Kws, Vws, (float*)d_out);
}